// Round 2
// baseline (825.395 us; speedup 1.0000x reference)
//
#include <hip/hip_runtime.h>
#include <stdint.h>

#define BATCH 16
#define NBOX  32768
#define PRE   4096
#define POST  512

typedef unsigned long long u64;
typedef unsigned int u32;

// ---------------------------------------------------------------------------
// K1: per-box key = (~score_bits)<<32 | index.  score = max over 3 classes.
// Ascending u64 order == descending score, ties -> ascending index (lax.top_k).
// ---------------------------------------------------------------------------
__global__ void k_keys(const float* __restrict__ cls, u64* __restrict__ keys) {
    int idx = blockIdx.x * blockDim.x + threadIdx.x; // over B*N
    if (idx >= BATCH * NBOX) return;
    const float* c = cls + (size_t)idx * 3;
    float s = fmaxf(fmaxf(c[0], c[1]), c[2]);
    u32 sb = __float_as_uint(s);          // scores >= 0 -> bit pattern monotonic
    int n = idx & (NBOX - 1);
    keys[idx] = ((u64)(~sb) << 32) | (u32)n;
}

// ---------------------------------------------------------------------------
// K2: LDS bitonic sort of a 4096-key chunk (ascending). 256 thr, 16 pairs/thr.
// ---------------------------------------------------------------------------
__global__ __launch_bounds__(256) void k_sort4096(const u64* __restrict__ in,
                                                  u64* __restrict__ out) {
    __shared__ u64 s[PRE];
    const u64* src = in + (size_t)blockIdx.x * PRE;
    u64* dst = out + (size_t)blockIdx.x * PRE;
    int tid = threadIdx.x;
    for (int i = tid; i < PRE; i += 256) s[i] = src[i];
    for (int k = 2; k <= PRE; k <<= 1) {
        for (int jj = k >> 1; jj > 0; jj >>= 1) {
            __syncthreads();
            for (int p = tid; p < PRE / 2; p += 256) {
                int i = 2 * p - (p & (jj - 1));
                int l = i + jj;
                bool asc = ((i & k) == 0);
                u64 a = s[i], b = s[l];
                if ((a > b) == asc) { s[i] = b; s[l] = a; }
            }
        }
    }
    __syncthreads();
    for (int i = tid; i < PRE; i += 256) dst[i] = s[i];
}

// ---------------------------------------------------------------------------
// K3: merge two ascending 4096-lists, keep the 4096 smallest, sorted.
// min(a[i], b[4095-i]) is bitonic and holds the 4096 smallest of the union;
// then a 12-substage bitonic clean sorts it ascending.
// ---------------------------------------------------------------------------
__global__ __launch_bounds__(256) void k_merge(const u64* __restrict__ in,
                                               u64* __restrict__ out, int npairs) {
    __shared__ u64 s[PRE];
    int b = blockIdx.x / npairs, p = blockIdx.x % npairs;
    const u64* A  = in + ((size_t)b * npairs * 2 + (size_t)p * 2) * PRE;
    const u64* Bp = A + PRE;
    u64* dst = out + ((size_t)b * npairs + p) * PRE;
    int tid = threadIdx.x;
    for (int i = tid; i < PRE; i += 256) {
        u64 a = A[i], bb = Bp[PRE - 1 - i];
        s[i] = a < bb ? a : bb;
    }
    for (int jj = PRE / 2; jj > 0; jj >>= 1) {
        __syncthreads();
        for (int p2 = tid; p2 < PRE / 2; p2 += 256) {
            int i = 2 * p2 - (p2 & (jj - 1));
            int l = i + jj;
            u64 a = s[i], bb = s[l];
            if (a > bb) { s[i] = bb; s[l] = a; }
        }
    }
    __syncthreads();
    for (int i = tid; i < PRE; i += 256) dst[i] = s[i];
}

// ---------------------------------------------------------------------------
// K4: greedy NMS per batch (1 WG of 1024 threads / batch) + output gather.
// Exact-FP replication of the reference IoU (rn ops, no fma contraction).
// ---------------------------------------------------------------------------
__global__ __launch_bounds__(1024) void k_nms(const u64* __restrict__ topkeys,
                                              const float* __restrict__ boxes,
                                              const float* __restrict__ cls,
                                              float* __restrict__ out) {
    __shared__ float sx1[PRE], sy1[PRE], sx2[PRE], sy2[PRE], sarea[PRE];
    __shared__ int   sorig[PRE];
    __shared__ u64   smask[PRE / 64];
    __shared__ int   ssel[POST];
    __shared__ int   scur;
    int b = blockIdx.x;
    int tid = threadIdx.x;
    const u64* keys = topkeys + (size_t)b * PRE;

    for (int i = tid; i < PRE; i += 1024) {
        u64 key = keys[i];
        int n = (int)(key & 0xffffffffULL);
        sorig[i] = n;
        const float* bp = boxes + ((size_t)b * NBOX + n) * 7;
        float cx = bp[0], cy = bp[1], dx = bp[3], dy = bp[4];
        float hx = __fmul_rn(dx, 0.5f), hy = __fmul_rn(dy, 0.5f);
        float x1 = __fsub_rn(cx, hx), x2 = __fadd_rn(cx, hx);
        float y1 = __fsub_rn(cy, hy), y2 = __fadd_rn(cy, hy);
        sx1[i] = x1; sx2[i] = x2; sy1[i] = y1; sy2[i] = y2;
        sarea[i] = __fmul_rn(__fsub_rn(x2, x1), __fsub_rn(y2, y1));
    }
    if (tid < PRE / 64) smask[tid] = ~0ULL;
    __syncthreads();

    int lane = tid & 63;
    int wv   = tid >> 6;   // 16 waves
    for (int r = 0; r < POST; ++r) {
        // find first active index (== argmax of masked sorted scores)
        if (tid < 64) {
            u64 w = smask[lane];
            u64 nz = __ballot(w != 0ULL);
            int j = -1;
            if (nz) {
                int fw = __ffsll(nz) - 1;
                int lo = __shfl((int)(w & 0xffffffffULL), fw);
                int hi = __shfl((int)(w >> 32), fw);
                u64 wf = ((u64)(u32)hi << 32) | (u32)lo;
                j = (fw << 6) + __ffsll(wf) - 1;
            }
            if (lane == 0) { scur = j; ssel[r] = j; }
        }
        __syncthreads();
        int j = scur;
        if (j < 0) { // nothing left: pad the rest and exit
            for (int k = r + tid; k < POST; k += 1024) ssel[k] = -1;
            __syncthreads();
            break;
        }
        float x1j = sx1[j], x2j = sx2[j], y1j = sy1[j], y2j = sy2[j], aj = sarea[j];
        // suppress: wave wv owns mask words [wv*4, wv*4+4)
        for (int wd = wv * 4; wd < wv * 4 + 4; ++wd) {
            u64 m = smask[wd];
            if (m == 0ULL) continue;        // wave-uniform skip
            int i = (wd << 6) + lane;
            float ix = fmaxf(__fsub_rn(fminf(sx2[i], x2j), fmaxf(sx1[i], x1j)), 0.0f);
            float iy = fmaxf(__fsub_rn(fminf(sy2[i], y2j), fmaxf(sy1[i], y1j)), 0.0f);
            float inter = __fmul_rn(ix, iy);
            float denom = __fadd_rn(__fsub_rn(__fadd_rn(sarea[i], aj), inter), 1e-8f);
            float iou = __fdiv_rn(inter, denom);
            u64 clr = __ballot(!(iou < 0.7f));  // matches active & (iou < T)
            if (lane == 0) smask[wd] = m & ~clr;
        }
        __syncthreads();
    }

    // outputs: rois | scores | labels(+1, as float), zeros/1 for padding
    const int R1 = BATCH * POST * 7;
    const int R2 = R1 + BATCH * POST;
    for (int k = tid; k < POST; k += 1024) {
        int j = ssel[k];
        float* ro = out + ((size_t)b * POST + k) * 7;
        float score = 0.0f, labelf = 1.0f;
        if (j >= 0) {
            int n = sorig[j];
            const float* bp = boxes + ((size_t)b * NBOX + n) * 7;
            #pragma unroll
            for (int c = 0; c < 7; ++c) ro[c] = bp[c];
            u64 key = keys[j];
            score = __uint_as_float(~(u32)(key >> 32));
            const float* cp = cls + ((size_t)b * NBOX + n) * 3;
            float c0 = cp[0], c1 = cp[1], c2 = cp[2];
            int lab = 0; float best = c0;
            if (c1 > best) { best = c1; lab = 1; }
            if (c2 > best) { lab = 2; }
            labelf = (float)(lab + 1);
        } else {
            #pragma unroll
            for (int c = 0; c < 7; ++c) ro[c] = 0.0f;
        }
        out[R1 + b * POST + k] = score;
        out[R2 + b * POST + k] = labelf;
    }
}

extern "C" void kernel_launch(void* const* d_in, const int* in_sizes, int n_in,
                              void* d_out, int out_size, void* d_ws, size_t ws_size,
                              hipStream_t stream) {
    const float* boxes = (const float*)d_in[0]; // (B,N,7)
    const float* cls   = (const float*)d_in[1]; // (B,N,3)
    float* out = (float*)d_out;
    u64* keysA = (u64*)d_ws;                        // 4 MB
    u64* keysB = keysA + (size_t)BATCH * NBOX;      // 4 MB

    k_keys<<<(BATCH * NBOX) / 256, 256, 0, stream>>>(cls, keysA);
    k_sort4096<<<BATCH * 8, 256, 0, stream>>>(keysA, keysB);   // 8 sorted chunks/batch
    k_merge<<<BATCH * 4, 256, 0, stream>>>(keysB, keysA, 4);   // 8 -> 4
    k_merge<<<BATCH * 2, 256, 0, stream>>>(keysA, keysB, 2);   // 4 -> 2
    k_merge<<<BATCH * 1, 256, 0, stream>>>(keysB, keysA, 1);   // 2 -> 1 (top-4096 sorted)
    k_nms<<<BATCH, 1024, 0, stream>>>(keysA, boxes, cls, out);
}

// Round 3
// 466.811 us; speedup vs baseline: 1.7682x; 1.7682x over previous
//
#include <hip/hip_runtime.h>
#include <stdint.h>

#define BATCH 16
#define NBOX  32768
#define PRE   4096
#define POST  512

typedef unsigned long long u64;
typedef unsigned int u32;

__device__ inline u64 shfl64(u64 v, int src) {
    int lo = __shfl((int)(v & 0xffffffffULL), src);
    int hi = __shfl((int)(v >> 32), src);
    return ((u64)(u32)hi << 32) | (u32)lo;
}

// ---------------------------------------------------------------------------
// K1: fused keygen + LDS bitonic sort of a 4096-key chunk (ascending).
// key = (~score_bits)<<32 | box_index  -> ascending == lax.top_k order.
// 1024 threads: 2 compare-exchanges per thread per substage.
// ---------------------------------------------------------------------------
__global__ __launch_bounds__(1024) void k_sortkeys4096(const float* __restrict__ cls,
                                                       u64* __restrict__ out) {
    __shared__ u64 s[PRE];
    int g = blockIdx.x;                 // global chunk: g = b*8 + c
    u64* dst = out + (size_t)g * PRE;
    int tid = threadIdx.x;
    for (int i = tid; i < PRE; i += 1024) {
        int idx = g * PRE + i;          // global box index (b*NBOX + n)
        const float* c = cls + (size_t)idx * 3;
        float sc = fmaxf(fmaxf(c[0], c[1]), c[2]);
        u32 sb = __float_as_uint(sc);   // scores >= 0 -> monotonic bits
        s[i] = ((u64)(~sb) << 32) | (u32)(idx & (NBOX - 1));
    }
    for (int k = 2; k <= PRE; k <<= 1) {
        for (int jj = k >> 1; jj > 0; jj >>= 1) {
            __syncthreads();
            for (int p = tid; p < PRE / 2; p += 1024) {
                int i = 2 * p - (p & (jj - 1));
                int l = i + jj;
                bool asc = ((i & k) == 0);
                u64 a = s[i], b = s[l];
                if ((a > b) == asc) { s[i] = b; s[l] = a; }
            }
        }
    }
    __syncthreads();
    for (int i = tid; i < PRE; i += 1024) dst[i] = s[i];
}

// ---------------------------------------------------------------------------
// K2: merge two ascending 4096-lists, keep smallest 4096, sorted.
// ---------------------------------------------------------------------------
__global__ __launch_bounds__(1024) void k_merge(const u64* __restrict__ in,
                                                u64* __restrict__ out, int npairs) {
    __shared__ u64 s[PRE];
    int b = blockIdx.x / npairs, p = blockIdx.x % npairs;
    const u64* A  = in + ((size_t)b * npairs * 2 + (size_t)p * 2) * PRE;
    const u64* Bp = A + PRE;
    u64* dst = out + ((size_t)b * npairs + p) * PRE;
    int tid = threadIdx.x;
    for (int i = tid; i < PRE; i += 1024) {
        u64 a = A[i], bb = Bp[PRE - 1 - i];
        s[i] = a < bb ? a : bb;
    }
    for (int jj = PRE / 2; jj > 0; jj >>= 1) {
        __syncthreads();
        for (int p2 = tid; p2 < PRE / 2; p2 += 1024) {
            int i = 2 * p2 - (p2 & (jj - 1));
            int l = i + jj;
            u64 a = s[i], bb = s[l];
            if (a > bb) { s[i] = bb; s[l] = a; }
        }
    }
    __syncthreads();
    for (int i = tid; i < PRE; i += 1024) dst[i] = s[i];
}

// ---------------------------------------------------------------------------
// K3: final merge (npairs==1) + emit sorted candidate coords SoA for the
// IoU matrix pass. Exact-FP box->corner math (rn ops, no fma contraction).
// ---------------------------------------------------------------------------
__global__ __launch_bounds__(1024) void k_merge_final(const u64* __restrict__ in,
                                                      u64* __restrict__ topkeys,
                                                      const float* __restrict__ boxes,
                                                      float* __restrict__ cx1,
                                                      float* __restrict__ cy1,
                                                      float* __restrict__ cx2,
                                                      float* __restrict__ cy2,
                                                      float* __restrict__ car) {
    __shared__ u64 s[PRE];
    int b = blockIdx.x;
    const u64* A  = in + (size_t)b * 2 * PRE;
    const u64* Bp = A + PRE;
    int tid = threadIdx.x;
    for (int i = tid; i < PRE; i += 1024) {
        u64 a = A[i], bb = Bp[PRE - 1 - i];
        s[i] = a < bb ? a : bb;
    }
    for (int jj = PRE / 2; jj > 0; jj >>= 1) {
        __syncthreads();
        for (int p2 = tid; p2 < PRE / 2; p2 += 1024) {
            int i = 2 * p2 - (p2 & (jj - 1));
            int l = i + jj;
            u64 a = s[i], bb = s[l];
            if (a > bb) { s[i] = bb; s[l] = a; }
        }
    }
    __syncthreads();
    for (int i = tid; i < PRE; i += 1024) {
        u64 key = s[i];
        topkeys[(size_t)b * PRE + i] = key;
        int n = (int)(key & 0xffffffffULL);
        const float* bp = boxes + ((size_t)b * NBOX + n) * 7;
        float cx = bp[0], cy = bp[1], dx = bp[3], dy = bp[4];
        float hx = __fmul_rn(dx, 0.5f), hy = __fmul_rn(dy, 0.5f);
        float x1 = __fsub_rn(cx, hx), x2 = __fadd_rn(cx, hx);
        float y1 = __fsub_rn(cy, hy), y2 = __fadd_rn(cy, hy);
        size_t o = (size_t)b * PRE + i;
        cx1[o] = x1; cy1[o] = y1; cx2[o] = x2; cy2[o] = y2;
        car[o] = __fmul_rn(__fsub_rn(x2, x1), __fsub_rn(y2, y1));
    }
}

// ---------------------------------------------------------------------------
// K4: pairwise suppression-matrix. WG = (i-block of 64 rows, batch).
// Row i gets 64-bit words wd in [i>>6, 63]; bit (j&63) of word wd set iff
// j>i and !(iou<0.7). Also emits per-64-row nonzero flag word.
// ---------------------------------------------------------------------------
__global__ __launch_bounds__(256) void k_iou(const float* __restrict__ cx1,
                                             const float* __restrict__ cy1,
                                             const float* __restrict__ cx2,
                                             const float* __restrict__ cy2,
                                             const float* __restrict__ car,
                                             u64* __restrict__ maskp,
                                             u64* __restrict__ flagbits) {
    __shared__ u32 fl[4];
    int blk = blockIdx.x;          // 0..63
    int b   = blockIdx.y;          // batch
    int tid = threadIdx.x;
    int w = tid >> 6, lane = tid & 63;
    size_t base = (size_t)b * PRE;

    // 16 rows per wave, wave-uniform coords -> scalar loads
    float rx1[16], ry1[16], rx2[16], ry2[16], ra[16];
    int i0 = blk * 64 + w * 16;
    #pragma unroll
    for (int r = 0; r < 16; ++r) {
        rx1[r] = cx1[base + i0 + r]; ry1[r] = cy1[base + i0 + r];
        rx2[r] = cx2[base + i0 + r]; ry2[r] = cy2[base + i0 + r];
        ra[r]  = car[base + i0 + r];
    }
    u32 nzbits = 0;
    for (int wd = blk; wd < 64; ++wd) {
        int j = wd * 64 + lane;
        float jx1 = cx1[base + j], jy1 = cy1[base + j];
        float jx2 = cx2[base + j], jy2 = cy2[base + j];
        float ja  = car[base + j];
        #pragma unroll
        for (int r = 0; r < 16; ++r) {
            int i = i0 + r;
            float ix = fmaxf(__fsub_rn(fminf(jx2, rx2[r]), fmaxf(jx1, rx1[r])), 0.0f);
            float iy = fmaxf(__fsub_rn(fminf(jy2, ry2[r]), fmaxf(jy1, ry1[r])), 0.0f);
            float inter = __fmul_rn(ix, iy);
            float denom = __fadd_rn(__fsub_rn(__fadd_rn(ja, ra[r]), inter), 1e-8f);
            float iou = __fdiv_rn(inter, denom);
            bool sup = (j > i) && !(iou < 0.7f);
            u64 m = __ballot(sup);
            if (lane == 0) maskp[((base + i) << 6) + wd] = m;
            nzbits |= (m != 0ULL) ? (1u << r) : 0u;
        }
    }
    if (lane == 0) fl[w] = nzbits;
    __syncthreads();
    if (tid == 0) {
        u64 word = (u64)fl[0] | ((u64)fl[1] << 16) | ((u64)fl[2] << 32) | ((u64)fl[3] << 48);
        flagbits[b * 64 + blk] = word;
    }
}

// ---------------------------------------------------------------------------
// K5: register-resident greedy walk (1 wave/batch) + output gather.
// Active mask: lane l holds candidates [l*64, l*64+64). Selection order is
// monotone ascending, so bits below the cursor are always clear.
// ---------------------------------------------------------------------------
__global__ __launch_bounds__(256) void k_walk(const u64* __restrict__ maskp,
                                              const u64* __restrict__ flagbits,
                                              const u64* __restrict__ topkeys,
                                              const float* __restrict__ boxes,
                                              const float* __restrict__ cls,
                                              float* __restrict__ out) {
    __shared__ int ssel[POST];
    __shared__ int scnt;
    int b = blockIdx.x;
    int tid = threadIdx.x;
    const u64* keys = topkeys + (size_t)b * PRE;

    if (tid < 64) {
        int lane = tid;
        u64 act = ~0ULL;
        u64 nzf = flagbits[b * 64 + lane];
        int cnt = 0;
        while (true) {
            u64 bal = __ballot(act != 0ULL);
            if (!bal) break;
            int fw = __ffsll(bal) - 1;
            u64 wsel = shfl64(act, fw);
            int i = (fw << 6) + __ffsll(wsel) - 1;
            if (lane == 0) ssel[cnt] = i;
            cnt++;
            if (cnt == POST) break;
            if (lane == fw) act &= ~(1ULL << (i & 63));
            u64 fword = shfl64(nzf, fw);
            if ((fword >> (i & 63)) & 1ULL) {
                u64 row = maskp[(((size_t)b * PRE + i) << 6) + lane];
                if (lane >= fw) act &= ~row;   // words < fw were never written
            }
        }
        if (lane == 0) scnt = cnt;
    }
    __syncthreads();
    int cnt = scnt;
    for (int k = tid; k < POST; k += 256) if (k >= cnt) ssel[k] = -1;
    __syncthreads();

    const int R1 = BATCH * POST * 7;
    const int R2 = R1 + BATCH * POST;
    for (int k = tid; k < POST; k += 256) {
        int j = ssel[k];
        float* ro = out + ((size_t)b * POST + k) * 7;
        float score = 0.0f, labelf = 1.0f;
        if (j >= 0) {
            u64 key = keys[j];
            int n = (int)(key & 0xffffffffULL);
            const float* bp = boxes + ((size_t)b * NBOX + n) * 7;
            #pragma unroll
            for (int c = 0; c < 7; ++c) ro[c] = bp[c];
            score = __uint_as_float(~(u32)(key >> 32));
            const float* cp = cls + ((size_t)b * NBOX + n) * 3;
            float c0 = cp[0], c1 = cp[1], c2 = cp[2];
            int lab = 0; float best = c0;
            if (c1 > best) { best = c1; lab = 1; }
            if (c2 > best) { lab = 2; }
            labelf = (float)(lab + 1);
        } else {
            #pragma unroll
            for (int c = 0; c < 7; ++c) ro[c] = 0.0f;
        }
        out[R1 + b * POST + k] = score;
        out[R2 + b * POST + k] = labelf;
    }
}

// ---------------------------------------------------------------------------
// Fallback NMS (round-0, proven): one 1024-thread WG per batch, LDS-resident.
// Used only if ws_size can't hold the 32 MB suppression matrix.
// ---------------------------------------------------------------------------
__global__ __launch_bounds__(1024) void k_nms(const u64* __restrict__ topkeys,
                                              const float* __restrict__ boxes,
                                              const float* __restrict__ cls,
                                              float* __restrict__ out) {
    __shared__ float sx1[PRE], sy1[PRE], sx2[PRE], sy2[PRE], sarea[PRE];
    __shared__ int   sorig[PRE];
    __shared__ u64   smask[PRE / 64];
    __shared__ int   ssel[POST];
    __shared__ int   scur;
    int b = blockIdx.x;
    int tid = threadIdx.x;
    const u64* keys = topkeys + (size_t)b * PRE;

    for (int i = tid; i < PRE; i += 1024) {
        u64 key = keys[i];
        int n = (int)(key & 0xffffffffULL);
        sorig[i] = n;
        const float* bp = boxes + ((size_t)b * NBOX + n) * 7;
        float cx = bp[0], cy = bp[1], dx = bp[3], dy = bp[4];
        float hx = __fmul_rn(dx, 0.5f), hy = __fmul_rn(dy, 0.5f);
        float x1 = __fsub_rn(cx, hx), x2 = __fadd_rn(cx, hx);
        float y1 = __fsub_rn(cy, hy), y2 = __fadd_rn(cy, hy);
        sx1[i] = x1; sx2[i] = x2; sy1[i] = y1; sy2[i] = y2;
        sarea[i] = __fmul_rn(__fsub_rn(x2, x1), __fsub_rn(y2, y1));
    }
    if (tid < PRE / 64) smask[tid] = ~0ULL;
    __syncthreads();

    int lane = tid & 63;
    int wv   = tid >> 6;
    for (int r = 0; r < POST; ++r) {
        if (tid < 64) {
            u64 w = smask[lane];
            u64 nz = __ballot(w != 0ULL);
            int j = -1;
            if (nz) {
                int fw = __ffsll(nz) - 1;
                u64 wf = shfl64(w, fw);
                j = (fw << 6) + __ffsll(wf) - 1;
            }
            if (lane == 0) { scur = j; ssel[r] = j; }
        }
        __syncthreads();
        int j = scur;
        if (j < 0) {
            for (int k = r + tid; k < POST; k += 1024) ssel[k] = -1;
            __syncthreads();
            break;
        }
        float x1j = sx1[j], x2j = sx2[j], y1j = sy1[j], y2j = sy2[j], aj = sarea[j];
        for (int wd = wv * 4; wd < wv * 4 + 4; ++wd) {
            u64 m = smask[wd];
            if (m == 0ULL) continue;
            int i = (wd << 6) + lane;
            float ix = fmaxf(__fsub_rn(fminf(sx2[i], x2j), fmaxf(sx1[i], x1j)), 0.0f);
            float iy = fmaxf(__fsub_rn(fminf(sy2[i], y2j), fmaxf(sy1[i], y1j)), 0.0f);
            float inter = __fmul_rn(ix, iy);
            float denom = __fadd_rn(__fsub_rn(__fadd_rn(sarea[i], aj), inter), 1e-8f);
            float iou = __fdiv_rn(inter, denom);
            u64 clr = __ballot(!(iou < 0.7f));
            if (lane == 0) smask[wd] = m & ~clr;
        }
        __syncthreads();
    }

    const int R1 = BATCH * POST * 7;
    const int R2 = R1 + BATCH * POST;
    for (int k = tid; k < POST; k += 1024) {
        int j = ssel[k];
        float* ro = out + ((size_t)b * POST + k) * 7;
        float score = 0.0f, labelf = 1.0f;
        if (j >= 0) {
            int n = sorig[j];
            const float* bp = boxes + ((size_t)b * NBOX + n) * 7;
            #pragma unroll
            for (int c = 0; c < 7; ++c) ro[c] = bp[c];
            u64 key = keys[j];
            score = __uint_as_float(~(u32)(key >> 32));
            const float* cp = cls + ((size_t)b * NBOX + n) * 3;
            float c0 = cp[0], c1 = cp[1], c2 = cp[2];
            int lab = 0; float best = c0;
            if (c1 > best) { best = c1; lab = 1; }
            if (c2 > best) { lab = 2; }
            labelf = (float)(lab + 1);
        } else {
            #pragma unroll
            for (int c = 0; c < 7; ++c) ro[c] = 0.0f;
        }
        out[R1 + b * POST + k] = score;
        out[R2 + b * POST + k] = labelf;
    }
}

extern "C" void kernel_launch(void* const* d_in, const int* in_sizes, int n_in,
                              void* d_out, int out_size, void* d_ws, size_t ws_size,
                              hipStream_t stream) {
    const float* boxes = (const float*)d_in[0]; // (B,N,7)
    const float* cls   = (const float*)d_in[1]; // (B,N,3)
    float* out = (float*)d_out;

    char* ws = (char*)d_ws;
    u64*   keysA = (u64*)(ws + 0);                       // 4 MB
    u64*   keysB = (u64*)(ws + 4194304);                 // 4 MB
    float* cx1   = (float*)(ws + 8388608);               // 5 x 256 KB coords
    float* cy1   = (float*)(ws + 8650752);
    float* cx2   = (float*)(ws + 8912896);
    float* cy2   = (float*)(ws + 9175040);
    float* car   = (float*)(ws + 9437184);
    u64*   flags = (u64*)(ws + 9699328);                 // 8 KB
    u64*   maskp = (u64*)(ws + 9707520);                 // 32 MB
    const size_t NEED = 9707520 + (size_t)BATCH * PRE * 64 * 8; // 43,261,952

    k_sortkeys4096<<<BATCH * 8, 1024, 0, stream>>>(cls, keysB);
    k_merge<<<BATCH * 4, 1024, 0, stream>>>(keysB, keysA, 4);   // 8 -> 4
    k_merge<<<BATCH * 2, 1024, 0, stream>>>(keysA, keysB, 2);   // 4 -> 2

    if (ws_size >= NEED) {
        k_merge_final<<<BATCH, 1024, 0, stream>>>(keysB, keysA, boxes,
                                                  cx1, cy1, cx2, cy2, car);
        k_iou<<<dim3(64, BATCH), 256, 0, stream>>>(cx1, cy1, cx2, cy2, car,
                                                   maskp, flags);
        k_walk<<<BATCH, 256, 0, stream>>>(maskp, flags, keysA, boxes, cls, out);
    } else {
        k_merge<<<BATCH, 1024, 0, stream>>>(keysB, keysA, 1);   // 2 -> 1
        k_nms<<<BATCH, 1024, 0, stream>>>(keysA, boxes, cls, out);
    }
}

// Round 4
// 312.150 us; speedup vs baseline: 2.6442x; 1.4955x over previous
//
#include <hip/hip_runtime.h>
#include <stdint.h>

#define BATCH 16
#define NBOX  32768
#define PRE   4096
#define POST  512

typedef unsigned long long u64;
typedef unsigned int u32;

__device__ inline u64 shfl64(u64 v, int src) {
    int lo = __shfl((int)(v & 0xffffffffULL), src);
    int hi = __shfl((int)(v >> 32), src);
    return ((u64)(u32)hi << 32) | (u32)lo;
}

// ---------------------------------------------------------------------------
// K1: fused keygen + LDS bitonic sort of a 4096-key chunk (ascending).
// key = (~score_bits)<<32 | box_index  -> ascending == lax.top_k order.
// ---------------------------------------------------------------------------
__global__ __launch_bounds__(1024) void k_sortkeys4096(const float* __restrict__ cls,
                                                       u64* __restrict__ out) {
    __shared__ u64 s[PRE];
    int g = blockIdx.x;                 // global chunk: g = b*8 + c
    u64* dst = out + (size_t)g * PRE;
    int tid = threadIdx.x;
    for (int i = tid; i < PRE; i += 1024) {
        int idx = g * PRE + i;          // global box index (b*NBOX + n)
        const float* c = cls + (size_t)idx * 3;
        float sc = fmaxf(fmaxf(c[0], c[1]), c[2]);
        u32 sb = __float_as_uint(sc);   // scores >= 0 -> monotonic bits
        s[i] = ((u64)(~sb) << 32) | (u32)(idx & (NBOX - 1));
    }
    for (int k = 2; k <= PRE; k <<= 1) {
        for (int jj = k >> 1; jj > 0; jj >>= 1) {
            __syncthreads();
            for (int p = tid; p < PRE / 2; p += 1024) {
                int i = 2 * p - (p & (jj - 1));
                int l = i + jj;
                bool asc = ((i & k) == 0);
                u64 a = s[i], b = s[l];
                if ((a > b) == asc) { s[i] = b; s[l] = a; }
            }
        }
    }
    __syncthreads();
    for (int i = tid; i < PRE; i += 1024) dst[i] = s[i];
}

// ---------------------------------------------------------------------------
// K2: merge two ascending 4096-lists, keep smallest 4096, sorted.
// ---------------------------------------------------------------------------
__global__ __launch_bounds__(1024) void k_merge(const u64* __restrict__ in,
                                                u64* __restrict__ out, int npairs) {
    __shared__ u64 s[PRE];
    int b = blockIdx.x / npairs, p = blockIdx.x % npairs;
    const u64* A  = in + ((size_t)b * npairs * 2 + (size_t)p * 2) * PRE;
    const u64* Bp = A + PRE;
    u64* dst = out + ((size_t)b * npairs + p) * PRE;
    int tid = threadIdx.x;
    for (int i = tid; i < PRE; i += 1024) {
        u64 a = A[i], bb = Bp[PRE - 1 - i];
        s[i] = a < bb ? a : bb;
    }
    for (int jj = PRE / 2; jj > 0; jj >>= 1) {
        __syncthreads();
        for (int p2 = tid; p2 < PRE / 2; p2 += 1024) {
            int i = 2 * p2 - (p2 & (jj - 1));
            int l = i + jj;
            u64 a = s[i], bb = s[l];
            if (a > bb) { s[i] = bb; s[l] = a; }
        }
    }
    __syncthreads();
    for (int i = tid; i < PRE; i += 1024) dst[i] = s[i];
}

// ---------------------------------------------------------------------------
// K3: per-candidate coord extraction (1 thread = 1 candidate, 64K threads)
// + zero the flag words. Exact-FP corner math (rn ops, no fma contraction).
// ---------------------------------------------------------------------------
__global__ __launch_bounds__(256) void k_coords(const u64* __restrict__ topkeys,
                                                const float* __restrict__ boxes,
                                                float* __restrict__ cx1,
                                                float* __restrict__ cy1,
                                                float* __restrict__ cx2,
                                                float* __restrict__ cy2,
                                                float* __restrict__ car,
                                                u64* __restrict__ flags) {
    int g = blockIdx.x * 256 + threadIdx.x;   // 0 .. B*PRE-1
    if (g < BATCH * 64) flags[g] = 0ULL;
    int b = g >> 12;                          // PRE = 4096
    u64 key = topkeys[g];
    int n = (int)(key & 0xffffffffULL);
    const float* bp = boxes + ((size_t)b * NBOX + n) * 7;
    float cx = bp[0], cy = bp[1], dx = bp[3], dy = bp[4];
    float hx = __fmul_rn(dx, 0.5f), hy = __fmul_rn(dy, 0.5f);
    float x1 = __fsub_rn(cx, hx), x2 = __fadd_rn(cx, hx);
    float y1 = __fsub_rn(cy, hy), y2 = __fadd_rn(cy, hy);
    cx1[g] = x1; cy1[g] = y1; cx2[g] = x2; cy2[g] = y2;
    car[g] = __fmul_rn(__fsub_rn(x2, x1), __fsub_rn(y2, y1));
}

// ---------------------------------------------------------------------------
// K4: pairwise suppression matrix, uniform tiles. Tile = (64-row block, word).
// blockIdx.x in [0,2080) decodes to (blk, wd) with wd >= blk (triangle).
// Division-free exact threshold: RN32(p/q) >= 0.7f  <=>  p > (0.7f-2^-25)*q,
// evaluated in f64 (25-bit * 24-bit product is exact in f64).
// ---------------------------------------------------------------------------
__global__ __launch_bounds__(256) void k_iou(const float* __restrict__ cx1,
                                             const float* __restrict__ cy1,
                                             const float* __restrict__ cx2,
                                             const float* __restrict__ cy2,
                                             const float* __restrict__ car,
                                             u64* __restrict__ maskp,
                                             u64* __restrict__ flags) {
    __shared__ float s1[64], s2[64], s3[64], s4[64], s5[64];
    int b = blockIdx.y;
    int t = blockIdx.x, blk = 0;
    while (t >= 64 - blk) { t -= 64 - blk; ++blk; }
    int wd = blk + t;
    size_t base = (size_t)b * PRE;
    int tid = threadIdx.x;
    if (tid < 64) {
        int i = blk * 64 + tid;
        s1[tid] = cx1[base + i]; s2[tid] = cy1[base + i];
        s3[tid] = cx2[base + i]; s4[tid] = cy2[base + i];
        s5[tid] = car[base + i];
    }
    __syncthreads();
    int w = tid >> 6, lane = tid & 63;
    int j = wd * 64 + lane;
    float jx1 = cx1[base + j], jy1 = cy1[base + j];
    float jx2 = cx2[base + j], jy2 = cy2[base + j];
    float ja  = car[base + j];
    const double M = (double)0.7f - 0x1p-25;   // exact rounding boundary
    u64 wavebits = 0;
    int r0 = w * 16;
    #pragma unroll 4
    for (int r = 0; r < 16; ++r) {
        int i = blk * 64 + r0 + r;
        float rx1 = s1[r0 + r], ry1 = s2[r0 + r];
        float rx2 = s3[r0 + r], ry2 = s4[r0 + r], ra = s5[r0 + r];
        float ix = fmaxf(__fsub_rn(fminf(jx2, rx2), fmaxf(jx1, rx1)), 0.0f);
        float iy = fmaxf(__fsub_rn(fminf(jy2, ry2), fmaxf(jy1, ry1)), 0.0f);
        float inter = __fmul_rn(ix, iy);
        bool cand = (j > i) && (inter > 0.0f);
        u64 m = 0;
        if (__ballot(cand)) {
            float ssum = __fadd_rn(ja, ra);
            float d    = __fsub_rn(ssum, inter);
            float q    = __fadd_rn(d, 1e-8f);
            bool sup = cand && ((double)inter > M * (double)q);
            m = __ballot(sup);
        }
        if (lane == 0) maskp[((base + i) << 6) + wd] = m;
        if (m) wavebits |= 1ULL << (r0 + r);
    }
    if (lane == 0 && wavebits)
        atomicOr((unsigned long long*)&flags[b * 64 + blk], wavebits);
}

// ---------------------------------------------------------------------------
// K5: register-resident greedy walk (1 wave/batch) + output gather.
// ---------------------------------------------------------------------------
__global__ __launch_bounds__(256) void k_walk(const u64* __restrict__ maskp,
                                              const u64* __restrict__ flagbits,
                                              const u64* __restrict__ topkeys,
                                              const float* __restrict__ boxes,
                                              const float* __restrict__ cls,
                                              float* __restrict__ out) {
    __shared__ int ssel[POST];
    __shared__ int scnt;
    int b = blockIdx.x;
    int tid = threadIdx.x;
    const u64* keys = topkeys + (size_t)b * PRE;

    if (tid < 64) {
        int lane = tid;
        u64 act = ~0ULL;
        u64 nzf = flagbits[b * 64 + lane];
        int cnt = 0;
        while (true) {
            u64 bal = __ballot(act != 0ULL);
            if (!bal) break;
            int fw = __ffsll(bal) - 1;
            u64 wsel = shfl64(act, fw);
            int i = (fw << 6) + __ffsll(wsel) - 1;
            if (lane == 0) ssel[cnt] = i;
            cnt++;
            if (cnt == POST) break;
            if (lane == fw) act &= ~(1ULL << (i & 63));
            u64 fword = shfl64(nzf, fw);
            if ((fword >> (i & 63)) & 1ULL) {
                u64 row = maskp[(((size_t)b * PRE + i) << 6) + lane];
                if (lane >= fw) act &= ~row;   // words < fw were never written
            }
        }
        if (lane == 0) scnt = cnt;
    }
    __syncthreads();
    int cnt = scnt;
    for (int k = tid; k < POST; k += 256) if (k >= cnt) ssel[k] = -1;
    __syncthreads();

    const int R1 = BATCH * POST * 7;
    const int R2 = R1 + BATCH * POST;
    for (int k = tid; k < POST; k += 256) {
        int j = ssel[k];
        float* ro = out + ((size_t)b * POST + k) * 7;
        float score = 0.0f, labelf = 1.0f;
        if (j >= 0) {
            u64 key = keys[j];
            int n = (int)(key & 0xffffffffULL);
            const float* bp = boxes + ((size_t)b * NBOX + n) * 7;
            #pragma unroll
            for (int c = 0; c < 7; ++c) ro[c] = bp[c];
            score = __uint_as_float(~(u32)(key >> 32));
            const float* cp = cls + ((size_t)b * NBOX + n) * 3;
            float c0 = cp[0], c1 = cp[1], c2 = cp[2];
            int lab = 0; float best = c0;
            if (c1 > best) { best = c1; lab = 1; }
            if (c2 > best) { lab = 2; }
            labelf = (float)(lab + 1);
        } else {
            #pragma unroll
            for (int c = 0; c < 7; ++c) ro[c] = 0.0f;
        }
        out[R1 + b * POST + k] = score;
        out[R2 + b * POST + k] = labelf;
    }
}

// ---------------------------------------------------------------------------
// Fallback NMS (round-0, proven): one 1024-thread WG per batch, LDS-resident.
// Used only if ws_size can't hold the 32 MB suppression matrix.
// ---------------------------------------------------------------------------
__global__ __launch_bounds__(1024) void k_nms(const u64* __restrict__ topkeys,
                                              const float* __restrict__ boxes,
                                              const float* __restrict__ cls,
                                              float* __restrict__ out) {
    __shared__ float sx1[PRE], sy1[PRE], sx2[PRE], sy2[PRE], sarea[PRE];
    __shared__ int   sorig[PRE];
    __shared__ u64   smask[PRE / 64];
    __shared__ int   ssel[POST];
    __shared__ int   scur;
    int b = blockIdx.x;
    int tid = threadIdx.x;
    const u64* keys = topkeys + (size_t)b * PRE;

    for (int i = tid; i < PRE; i += 1024) {
        u64 key = keys[i];
        int n = (int)(key & 0xffffffffULL);
        sorig[i] = n;
        const float* bp = boxes + ((size_t)b * NBOX + n) * 7;
        float cx = bp[0], cy = bp[1], dx = bp[3], dy = bp[4];
        float hx = __fmul_rn(dx, 0.5f), hy = __fmul_rn(dy, 0.5f);
        float x1 = __fsub_rn(cx, hx), x2 = __fadd_rn(cx, hx);
        float y1 = __fsub_rn(cy, hy), y2 = __fadd_rn(cy, hy);
        sx1[i] = x1; sx2[i] = x2; sy1[i] = y1; sy2[i] = y2;
        sarea[i] = __fmul_rn(__fsub_rn(x2, x1), __fsub_rn(y2, y1));
    }
    if (tid < PRE / 64) smask[tid] = ~0ULL;
    __syncthreads();

    int lane = tid & 63;
    int wv   = tid >> 6;
    for (int r = 0; r < POST; ++r) {
        if (tid < 64) {
            u64 w = smask[lane];
            u64 nz = __ballot(w != 0ULL);
            int j = -1;
            if (nz) {
                int fw = __ffsll(nz) - 1;
                u64 wf = shfl64(w, fw);
                j = (fw << 6) + __ffsll(wf) - 1;
            }
            if (lane == 0) { scur = j; ssel[r] = j; }
        }
        __syncthreads();
        int j = scur;
        if (j < 0) {
            for (int k = r + tid; k < POST; k += 1024) ssel[k] = -1;
            __syncthreads();
            break;
        }
        float x1j = sx1[j], x2j = sx2[j], y1j = sy1[j], y2j = sy2[j], aj = sarea[j];
        for (int wd = wv * 4; wd < wv * 4 + 4; ++wd) {
            u64 m = smask[wd];
            if (m == 0ULL) continue;
            int i = (wd << 6) + lane;
            float ix = fmaxf(__fsub_rn(fminf(sx2[i], x2j), fmaxf(sx1[i], x1j)), 0.0f);
            float iy = fmaxf(__fsub_rn(fminf(sy2[i], y2j), fmaxf(sy1[i], y1j)), 0.0f);
            float inter = __fmul_rn(ix, iy);
            float denom = __fadd_rn(__fsub_rn(__fadd_rn(sarea[i], aj), inter), 1e-8f);
            float iou = __fdiv_rn(inter, denom);
            u64 clr = __ballot(!(iou < 0.7f));
            if (lane == 0) smask[wd] = m & ~clr;
        }
        __syncthreads();
    }

    const int R1 = BATCH * POST * 7;
    const int R2 = R1 + BATCH * POST;
    for (int k = tid; k < POST; k += 1024) {
        int j = ssel[k];
        float* ro = out + ((size_t)b * POST + k) * 7;
        float score = 0.0f, labelf = 1.0f;
        if (j >= 0) {
            int n = sorig[j];
            const float* bp = boxes + ((size_t)b * NBOX + n) * 7;
            #pragma unroll
            for (int c = 0; c < 7; ++c) ro[c] = bp[c];
            u64 key = keys[j];
            score = __uint_as_float(~(u32)(key >> 32));
            const float* cp = cls + ((size_t)b * NBOX + n) * 3;
            float c0 = cp[0], c1 = cp[1], c2 = cp[2];
            int lab = 0; float best = c0;
            if (c1 > best) { best = c1; lab = 1; }
            if (c2 > best) { lab = 2; }
            labelf = (float)(lab + 1);
        } else {
            #pragma unroll
            for (int c = 0; c < 7; ++c) ro[c] = 0.0f;
        }
        out[R1 + b * POST + k] = score;
        out[R2 + b * POST + k] = labelf;
    }
}

extern "C" void kernel_launch(void* const* d_in, const int* in_sizes, int n_in,
                              void* d_out, int out_size, void* d_ws, size_t ws_size,
                              hipStream_t stream) {
    const float* boxes = (const float*)d_in[0]; // (B,N,7)
    const float* cls   = (const float*)d_in[1]; // (B,N,3)
    float* out = (float*)d_out;

    char* ws = (char*)d_ws;
    u64*   keysA = (u64*)(ws + 0);                       // 4 MB
    u64*   keysB = (u64*)(ws + 4194304);                 // 4 MB
    float* cx1   = (float*)(ws + 8388608);               // 5 x 256 KB coords
    float* cy1   = (float*)(ws + 8650752);
    float* cx2   = (float*)(ws + 8912896);
    float* cy2   = (float*)(ws + 9175040);
    float* car   = (float*)(ws + 9437184);
    u64*   flags = (u64*)(ws + 9699328);                 // 8 KB
    u64*   maskp = (u64*)(ws + 9707520);                 // 32 MB
    const size_t NEED = 9707520 + (size_t)BATCH * PRE * 64 * 8; // 43,261,952

    k_sortkeys4096<<<BATCH * 8, 1024, 0, stream>>>(cls, keysB);
    k_merge<<<BATCH * 4, 1024, 0, stream>>>(keysB, keysA, 4);   // 8 -> 4
    k_merge<<<BATCH * 2, 1024, 0, stream>>>(keysA, keysB, 2);   // 4 -> 2

    if (ws_size >= NEED) {
        k_merge<<<BATCH, 1024, 0, stream>>>(keysB, keysA, 1);   // 2 -> 1: topkeys
        k_coords<<<(BATCH * PRE) / 256, 256, 0, stream>>>(keysA, boxes,
                                                          cx1, cy1, cx2, cy2, car, flags);
        k_iou<<<dim3(2080, BATCH), 256, 0, stream>>>(cx1, cy1, cx2, cy2, car,
                                                     maskp, flags);
        k_walk<<<BATCH, 256, 0, stream>>>(maskp, flags, keysA, boxes, cls, out);
    } else {
        k_merge<<<BATCH, 1024, 0, stream>>>(keysB, keysA, 1);
        k_nms<<<BATCH, 1024, 0, stream>>>(keysA, boxes, cls, out);
    }
}